// Round 8
// baseline (2027.811 us; speedup 1.0000x reference)
//
#include <hip/hip_runtime.h>

typedef unsigned short u16;
typedef __bf16 bf16x8 __attribute__((ext_vector_type(8)));
typedef float f32x4 __attribute__((ext_vector_type(4)));

#define L_ 4
#define D_ 768
#define T_ 1024
#define B_ 2
#define H_ 12
#define DK_ 64
#define FF_ 3072
#define V_ 50257

__device__ __forceinline__ float bf2f(u16 u){ return __uint_as_float(((unsigned)u) << 16); }
__device__ __forceinline__ u16 f2bf(float f){
  unsigned x = __float_as_uint(f);
  return (u16)((x + 0x7fffu + ((x >> 16) & 1u)) >> 16);   // RNE
}

// ---- input dtype probe: f32 (flag=1) or bf16 (flag=0). Proven f32 on HW; kept as insurance. ----
__global__ __launch_bounds__(256) void detect_k(const u16* __restrict__ w, int* __restrict__ flag){
  __shared__ int s;
  if (threadIdx.x == 0) s = 0;
  __syncthreads();
  int bad = 0;
  for (int j = threadIdx.x; j < 4096; j += 256){
    int e = (w[j] >> 7) & 0xFF;
    if (e >= 0xC0) bad = 1;      // impossible exponent for 0.02-scale weights; certain for f32 mantissa halves
  }
  if (bad) atomicOr(&s, 1);
  __syncthreads();
  if (threadIdx.x == 0) flag[0] = s;
}

__device__ __forceinline__ float rdin(const void* p, long i, bool wf){
  return wf ? ((const float*)p)[i] : bf2f(((const u16*)p)[i]);
}

// ---------------- embedding: x = tok[id] + pos[t] (f32 residual stream) ----------------
__global__ __launch_bounds__(256) void embed_k(const int* __restrict__ ids,
    const void* __restrict__ tok, const void* __restrict__ pos, float* __restrict__ x,
    const int* __restrict__ dflag){
  bool wf = dflag[0] != 0;
  int row = blockIdx.x; int t = row & (T_-1);
  long id = ids[row];
  float* xr = x + (size_t)row * D_;
  for (int d = threadIdx.x; d < D_; d += 256)
    xr[d] = rdin(tok, id * (long)D_ + d, wf) + rdin(pos, (long)t * D_ + d, wf);
}

// ---------------- layernorm: f32 x -> bf16 h ----------------
__global__ __launch_bounds__(256) void ln_k(const float* __restrict__ x,
    const void* __restrict__ g, const void* __restrict__ bb, long goff, u16* __restrict__ out,
    const int* __restrict__ dflag){
  __shared__ float red[8];
  bool wf = dflag[0] != 0;
  int row = blockIdx.x, tid = threadIdx.x;
  const float* xr = x + (size_t)row * D_;
  float v[3]; float s = 0.f, s2 = 0.f;
  #pragma unroll
  for (int i = 0; i < 3; ++i){ float t = xr[tid + i*256]; v[i] = t; s += t; s2 += t*t; }
  #pragma unroll
  for (int o = 1; o < 64; o <<= 1){ s += __shfl_xor(s, o, 64); s2 += __shfl_xor(s2, o, 64); }
  if ((tid & 63) == 0){ red[tid >> 6] = s; red[(tid >> 6) + 4] = s2; }
  __syncthreads();
  s  = red[0] + red[1] + red[2] + red[3];
  s2 = red[4] + red[5] + red[6] + red[7];
  float mean = s * (1.f / D_);
  float var  = s2 * (1.f / D_) - mean * mean;
  float rstd = rsqrtf(var + 1e-5f);
  u16* orow = out + (size_t)row * D_;
  #pragma unroll
  for (int i = 0; i < 3; ++i){
    int d = tid + i*256;
    orow[d] = f2bf((v[i] - mean) * rstd * rdin(g, goff + d, wf) + rdin(bb, goff + d, wf));
  }
}

// ---------------- causal row softmax: f32 scores -> f32 attn (OUTPUT) + bf16 probs (scratch) ----------------
__global__ __launch_bounds__(256) void softmax_k(const float* __restrict__ scores,
    float* __restrict__ attnf, u16* __restrict__ probsb){
  __shared__ float red[4];
  int r = blockIdx.x, tid = threadIdx.x;
  int q = r & (T_-1);
  const float* srow = scores + (size_t)r * T_;
  float* arow = attnf + (size_t)r * T_;
  u16* prow = probsb + (size_t)r * T_;
  int n = q + 1;
  float sv[4]; float mx = -1e30f;
  #pragma unroll
  for (int i = 0; i < 4; ++i){ int k = tid + i*256;
    float t = (k < n) ? srow[k] : -1e30f; sv[i] = t; mx = fmaxf(mx, t); }
  #pragma unroll
  for (int o = 1; o < 64; o <<= 1) mx = fmaxf(mx, __shfl_xor(mx, o, 64));
  if ((tid & 63) == 0) red[tid >> 6] = mx;
  __syncthreads();
  mx = fmaxf(fmaxf(red[0], red[1]), fmaxf(red[2], red[3]));
  __syncthreads();
  float e[4]; float sum = 0.f;
  #pragma unroll
  for (int i = 0; i < 4; ++i){ int k = tid + i*256;
    float t = (k < n) ? expf(sv[i] - mx) : 0.f; e[i] = t; sum += t; }
  #pragma unroll
  for (int o = 1; o < 64; o <<= 1) sum += __shfl_xor(sum, o, 64);
  if ((tid & 63) == 0) red[tid >> 6] = sum;
  __syncthreads();
  sum = red[0] + red[1] + red[2] + red[3];
  float inv = 1.f / sum;
  #pragma unroll
  for (int i = 0; i < 4; ++i){ int k = tid + i*256;
    float p = (k < n) ? e[i] * inv : 0.f;
    arow[k] = p;
    prow[k] = f2bf(p);
  }
}

// ---------------- transpose proj_w [768][V] -> bf16 [V][768] ----------------
__global__ __launch_bounds__(256) void transpose_k(const void* __restrict__ in, u16* __restrict__ outp,
                                                   int R, int C, const int* __restrict__ dflag){
  __shared__ u16 tile[32][33];
  bool wf = dflag[0] != 0;
  int c0 = blockIdx.x * 32, r0 = blockIdx.y * 32;
  int lx = threadIdx.x & 31, ly = threadIdx.x >> 5;
  #pragma unroll
  for (int i = 0; i < 4; ++i){
    int r = r0 + ly + i*8, c = c0 + lx;
    tile[ly + i*8][lx] = (c < C) ? f2bf(rdin(in, (long)r * C + c, wf)) : (u16)0;
  }
  __syncthreads();
  #pragma unroll
  for (int i = 0; i < 4; ++i){
    int c = c0 + ly + i*8, r = r0 + lx;
    if (c < C) outp[(size_t)c * R + r] = tile[lx][ly + i*8];
  }
}

// ---------------- generic bf16 MFMA GEMM (HW-verified fragment maps) ----------------
// C[M,N] = epi(scale*(A@W) + bias). A: bf16. W/bias raw (dtype per dflag) or bf16 (dflag=null... via wf).
// EPI: 0 bf16 store, 1 gelu->bf16, 2 f32 residual +=, 3 f32 store.
template<int EPI, bool BTRANS, bool CAUSAL>
__global__ __launch_bounds__(256) void gemm_k(
    const u16* __restrict__ A, const void* __restrict__ W, const void* __restrict__ bias,
    long welem, long belem,
    u16* __restrict__ Cbf, float* __restrict__ Cf32, const int* __restrict__ dflag,
    int N, int K, int lda, int ldw, int ldc,
    long sAb, long sAh, long sWb, long sWh, long sCb, long sCh, float scale)
{
  int m0 = blockIdx.y * 64;
  int n0 = blockIdx.x * 64;
  if (CAUSAL && n0 > m0) return;
  const bool wf = dflag && (dflag[0] != 0);
  int z = blockIdx.z;
  int b = z / H_, hh = z % H_;
  const u16* Ab = A + (size_t)((long)b * sAb + (long)hh * sAh);
  long Woff = welem + (long)b * sWb + (long)hh * sWh;
  size_t Coff = (size_t)((long)b * sCb + (long)hh * sCh);

  __shared__ __align__(16) u16 As[64][72];
  __shared__ __align__(16) u16 Ws[64][72];

  int tid = threadIdx.x;
  int lane = tid & 63, wid = tid >> 6;
  int wr = wid >> 1, wc = wid & 1;
  int sr = tid >> 3;            // 0..31
  int sc = (tid & 7) << 3;      // 0..56

  f32x4 acc[2][2];
  #pragma unroll
  for (int i = 0; i < 2; ++i)
    #pragma unroll
    for (int j = 0; j < 2; ++j) acc[i][j] = (f32x4){0.f, 0.f, 0.f, 0.f};

  for (int k0 = 0; k0 < K; k0 += 64){
    {
      const u16* ga = Ab + (size_t)(m0 + sr) * lda + k0 + sc;
      *(int4*)(&As[sr][sc])      = *(const int4*)ga;
      *(int4*)(&As[sr + 32][sc]) = *(const int4*)(ga + (size_t)32 * lda);
    }
    if (BTRANS){
      const u16* Wb = (const u16*)W + Woff;
      int4 zv; zv.x = zv.y = zv.z = zv.w = 0;
      int n = n0 + sr;
      const u16* gw = Wb + (size_t)n * ldw + k0 + sc;
      *(int4*)(&Ws[sr][sc])      = (n      < N) ? *(const int4*)gw                      : zv;
      *(int4*)(&Ws[sr + 32][sc]) = (n + 32 < N) ? *(const int4*)(gw + (size_t)32 * ldw) : zv;
    } else if (wf){
      const float* Wb = (const float*)W + Woff;
      const float* gw = Wb + (size_t)(k0 + sr) * ldw + n0 + sc;
      if ((ldw & 3) == 0){
        float4 t0 = *(const float4*)gw;
        float4 t1 = *(const float4*)(gw + 4);
        Ws[sc+0][sr] = f2bf(t0.x); Ws[sc+1][sr] = f2bf(t0.y);
        Ws[sc+2][sr] = f2bf(t0.z); Ws[sc+3][sr] = f2bf(t0.w);
        Ws[sc+4][sr] = f2bf(t1.x); Ws[sc+5][sr] = f2bf(t1.y);
        Ws[sc+6][sr] = f2bf(t1.z); Ws[sc+7][sr] = f2bf(t1.w);
        t0 = *(const float4*)(gw + (size_t)32 * ldw);
        t1 = *(const float4*)(gw + (size_t)32 * ldw + 4);
        Ws[sc+0][sr+32] = f2bf(t0.x); Ws[sc+1][sr+32] = f2bf(t0.y);
        Ws[sc+2][sr+32] = f2bf(t0.z); Ws[sc+3][sr+32] = f2bf(t0.w);
        Ws[sc+4][sr+32] = f2bf(t1.x); Ws[sc+5][sr+32] = f2bf(t1.y);
        Ws[sc+6][sr+32] = f2bf(t1.z); Ws[sc+7][sr+32] = f2bf(t1.w);
      } else {
        #pragma unroll
        for (int j = 0; j < 8; ++j){
          bool ok = (n0 + sc + j) < N;
          Ws[sc + j][sr]      = ok ? f2bf(gw[j])                    : (u16)0;
          Ws[sc + j][sr + 32] = ok ? f2bf(gw[j + (size_t)32 * ldw]) : (u16)0;
        }
      }
    } else {
      const u16* Wb = (const u16*)W + Woff;
      const u16* gw = Wb + (size_t)(k0 + sr) * ldw + n0 + sc;
      if ((ldw & 7) == 0){
        u16 tmp[8];
        *(int4*)tmp = *(const int4*)gw;
        #pragma unroll
        for (int j = 0; j < 8; ++j) Ws[sc + j][sr] = tmp[j];
        *(int4*)tmp = *(const int4*)(gw + (size_t)32 * ldw);
        #pragma unroll
        for (int j = 0; j < 8; ++j) Ws[sc + j][sr + 32] = tmp[j];
      } else {
        #pragma unroll
        for (int j = 0; j < 8; ++j){
          bool ok = (n0 + sc + j) < N;
          Ws[sc + j][sr]      = ok ? gw[j]                    : (u16)0;
          Ws[sc + j][sr + 32] = ok ? gw[j + (size_t)32 * ldw] : (u16)0;
        }
      }
    }
    __syncthreads();
    #pragma unroll
    for (int kk = 0; kk < 2; ++kk){
      int ko = kk * 32 + ((lane >> 4) << 3);
      bf16x8 af[2], bfr[2];
      #pragma unroll
      for (int mi = 0; mi < 2; ++mi)
        af[mi] = *(const bf16x8*)(&As[wr*32 + mi*16 + (lane & 15)][ko]);
      #pragma unroll
      for (int ni = 0; ni < 2; ++ni)
        bfr[ni] = *(const bf16x8*)(&Ws[wc*32 + ni*16 + (lane & 15)][ko]);
      #pragma unroll
      for (int mi = 0; mi < 2; ++mi)
        #pragma unroll
        for (int ni = 0; ni < 2; ++ni)
          acc[mi][ni] = __builtin_amdgcn_mfma_f32_16x16x32_bf16(af[mi], bfr[ni], acc[mi][ni], 0, 0, 0);
    }
    __syncthreads();
  }
  // epilogue: C/D map col=lane&15, row=4*(lane>>4)+r  (HW-verified conv0)
  #pragma unroll
  for (int ni = 0; ni < 2; ++ni){
    int col = n0 + wc*32 + ni*16 + (lane & 15);
    if (col >= N) continue;
    float bvv = 0.f;
    if (bias) bvv = wf ? ((const float*)bias)[belem + col] : bf2f(((const u16*)bias)[belem + col]);
    #pragma unroll
    for (int mi = 0; mi < 2; ++mi){
      int rbase = m0 + wr*32 + mi*16 + ((lane >> 4) << 2);
      #pragma unroll
      for (int r = 0; r < 4; ++r){
        int row = rbase + r;
        float v = acc[mi][ni][r] * scale + bvv;
        size_t idx = Coff + (size_t)row * ldc + col;
        if (EPI == 0)      Cbf[idx] = f2bf(v);
        else if (EPI == 1){ float gg = 0.5f * v * (1.f + erff(v * 0.70710678118654752f)); Cbf[idx] = f2bf(gg); }
        else if (EPI == 2) Cf32[idx] += v;
        else               Cf32[idx] = v;
      }
    }
  }
}

extern "C" void kernel_launch(void* const* d_in, const int* in_sizes, int n_in,
                              void* d_out, int out_size, void* d_ws, size_t ws_size,
                              hipStream_t stream)
{
  (void)in_sizes; (void)n_in; (void)out_size;
  const int* ids = (const int*)d_in[0];
  const void* tok = d_in[1];  const void* pos = d_in[2];
  const void* ln1g = d_in[3]; const void* ln1b = d_in[4];
  const void* wq = d_in[5];   const void* bq = d_in[6];
  const void* wk = d_in[7];   const void* bk = d_in[8];
  const void* wv = d_in[9];   const void* bv = d_in[10];
  const void* wo = d_in[11];  const void* bo = d_in[12];
  const void* ln2g = d_in[13]; const void* ln2b = d_in[14];
  const void* w1 = d_in[15];  const void* b1 = d_in[16];
  const void* w2 = d_in[17];  const void* b2 = d_in[18];
  const void* lnfg = d_in[19]; const void* lnfb = d_in[20];
  const void* pw = d_in[21];

  // ---------- memory map: d_out is FLOAT32, 512,368,640 B ----------
  //   logits f32  [0, 411,705,344)                 (written LAST by projection)
  //   attn   f32  [411,705,344, 512,368,640)       (softmax writes each layer; layer 3 persists)
  // scratch inside the logits region (all dead before the projection writes):
  //   scores f32  [0, 100,663,296)
  //   x      f32  [100,663,296, 106,954,752)
  //   qb,kb,vb,ctx bf16  [106,954,752, 119,537,664)
  //   ff     bf16 [119,537,664, 132,120,576)
  //   probsb bf16 [132,120,576, 182,452,224)
  // ws: dflag(256B) + h bf16(3.15MB, live during projection) + projT(77.2MB optional)
  char* ob = (char*)d_out;
  float* logitsF = (float*)ob;
  float* attnF   = (float*)(ob + 411705344);
  float* scores  = (float*)ob;
  float* x   = (float*)(ob + 100663296);
  u16* qb    = (u16*)(ob + 106954752);
  u16* kb    = (u16*)(ob + 110100480);
  u16* vb    = (u16*)(ob + 113246208);
  u16* ctx   = (u16*)(ob + 116391936);
  u16* ff    = (u16*)(ob + 119537664);
  u16* probsb= (u16*)(ob + 132120576);
  char* wsp = (char*)d_ws;
  int* dflag = (int*)wsp;
  u16* h     = (u16*)(wsp + 256);
  u16* projT = (u16*)(wsp + 256 + 3145728);
  bool useT = (ws_size >= (size_t)256 + 3145728 + (size_t)V_ * D_ * 2);

  const int BT = B_ * T_;
  detect_k<<<1, 256, 0, stream>>>((const u16*)tok, dflag);
  if (useT){
    dim3 gt((V_ + 31) / 32, D_ / 32);
    transpose_k<<<gt, 256, 0, stream>>>(pw, projT, D_, V_, dflag);
  }
  embed_k<<<BT, 256, 0, stream>>>(ids, tok, pos, x, dflag);

  dim3 gD(D_/64, BT/64);            // 12 x 32
  dim3 gFF(FF_/64, BT/64);          // 48 x 32
  dim3 gS(T_/64, T_/64, B_*H_);     // 16 x 16 x 24 (causal-skipped above diagonal)
  dim3 gC(1, T_/64, B_*H_);

  const long sQKb = (long)T_ * D_, sQKh = DK_;
  const long sSb  = (long)H_ * T_ * T_, sSh = (long)T_ * T_;

  for (int l = 0; l < L_; ++l){
    long oW = (long)l * D_ * D_, oB = (long)l * D_;
    long oW1 = (long)l * D_ * FF_, oB1 = (long)l * FF_;
    long oW2 = (long)l * FF_ * D_;
    ln_k<<<BT, 256, 0, stream>>>(x, ln1g, ln1b, oB, h, dflag);
    gemm_k<0,false,false><<<gD, 256, 0, stream>>>(h, wq, bq, oW, oB, qb, nullptr, dflag,
        D_, D_, D_, D_, D_, 0,0,0,0,0,0, 1.f);
    gemm_k<0,false,false><<<gD, 256, 0, stream>>>(h, wk, bk, oW, oB, kb, nullptr, dflag,
        D_, D_, D_, D_, D_, 0,0,0,0,0,0, 1.f);
    gemm_k<0,false,false><<<gD, 256, 0, stream>>>(h, wv, bv, oW, oB, vb, nullptr, dflag,
        D_, D_, D_, D_, D_, 0,0,0,0,0,0, 1.f);
    // scores = (Q @ K^T)/8 (f32, causal tiles only)
    gemm_k<3,true,true><<<gS, 256, 0, stream>>>(qb, kb, nullptr, 0, 0, nullptr, scores, nullptr,
        T_, DK_, D_, D_, T_, sQKb, sQKh, sQKb, sQKh, sSb, sSh, 0.125f);
    // softmax: f32 probs -> attn OUTPUT region (+ bf16 scratch for PV GEMM)
    softmax_k<<<B_*H_*T_, 256, 0, stream>>>(scores, attnF, probsb);
    // ctx = P @ V
    gemm_k<0,false,false><<<gC, 256, 0, stream>>>(probsb, vb, nullptr, 0, 0, ctx, nullptr, nullptr,
        DK_, T_, T_, D_, D_, sSb, sSh, sQKb, sQKh, sQKb, sQKh, 1.f);
    // x += ctx @ wo + bo
    gemm_k<2,false,false><<<gD, 256, 0, stream>>>(ctx, wo, bo, oW, oB, nullptr, x, dflag,
        D_, D_, D_, D_, D_, 0,0,0,0,0,0, 1.f);
    ln_k<<<BT, 256, 0, stream>>>(x, ln2g, ln2b, oB, h, dflag);
    // ff = gelu(h @ w1 + b1)
    gemm_k<1,false,false><<<gFF, 256, 0, stream>>>(h, w1, b1, oW1, oB1, ff, nullptr, dflag,
        FF_, D_, D_, FF_, FF_, 0,0,0,0,0,0, 1.f);
    // x += ff @ w2 + b2
    gemm_k<2,false,false><<<gD, 256, 0, stream>>>(ff, w2, b2, oW2, oB, nullptr, x, dflag,
        D_, FF_, FF_, D_, D_, 0,0,0,0,0,0, 1.f);
  }
  ln_k<<<BT, 256, 0, stream>>>(x, lnfg, lnfb, 0, h, dflag);
  // logits (f32) = h @ proj_w
  dim3 gP((V_ + 63) / 64, BT / 64);
  if (useT)
    gemm_k<3,true,false><<<gP, 256, 0, stream>>>(h, projT, nullptr, 0, 0, nullptr, logitsF, nullptr,
        V_, D_, D_, D_, V_, 0,0,0,0,0,0, 1.f);
  else
    gemm_k<3,false,false><<<gP, 256, 0, stream>>>(h, pw, nullptr, 0, 0, nullptr, logitsF, dflag,
        V_, D_, D_, V_, V_, 0,0,0,0,0,0, 1.f);
}

// Round 9
// 2002.583 us; speedup vs baseline: 1.0126x; 1.0126x over previous
//
#include <hip/hip_runtime.h>

typedef unsigned short u16;
typedef __bf16 bf16x8 __attribute__((ext_vector_type(8)));
typedef float f32x4 __attribute__((ext_vector_type(4)));

#define L_ 4
#define D_ 768
#define T_ 1024
#define B_ 2
#define H_ 12
#define DK_ 64
#define FF_ 3072
#define V_ 50257

__device__ __forceinline__ float bf2f(u16 u){ return __uint_as_float(((unsigned)u) << 16); }
__device__ __forceinline__ u16 f2bf(float f){
  unsigned x = __float_as_uint(f);
  return (u16)((x + 0x7fffu + ((x >> 16) & 1u)) >> 16);   // RNE
}

// ---- input dtype probe: f32 (flag=1) or bf16 (flag=0). HW-proven f32; kept as insurance. ----
__global__ __launch_bounds__(256) void detect_k(const u16* __restrict__ w, int* __restrict__ flag){
  __shared__ int s;
  if (threadIdx.x == 0) s = 0;
  __syncthreads();
  int bad = 0;
  for (int j = threadIdx.x; j < 4096; j += 256){
    int e = (w[j] >> 7) & 0xFF;
    if (e >= 0xC0) bad = 1;
  }
  if (bad) atomicOr(&s, 1);
  __syncthreads();
  if (threadIdx.x == 0) flag[0] = s;
}

__device__ __forceinline__ float rdin(const void* p, long i, bool wf){
  return wf ? ((const float*)p)[i] : bf2f(((const u16*)p)[i]);
}

// ---------------- embedding ----------------
__global__ __launch_bounds__(256) void embed_k(const int* __restrict__ ids,
    const void* __restrict__ tok, const void* __restrict__ pos, float* __restrict__ x,
    const int* __restrict__ dflag){
  bool wf = dflag[0] != 0;
  int row = blockIdx.x; int t = row & (T_-1);
  long id = ids[row];
  float* xr = x + (size_t)row * D_;
  for (int d = threadIdx.x; d < D_; d += 256)
    xr[d] = rdin(tok, id * (long)D_ + d, wf) + rdin(pos, (long)t * D_ + d, wf);
}

// ---------------- layernorm: f32 x -> bf16 h ----------------
__global__ __launch_bounds__(256) void ln_k(const float* __restrict__ x,
    const void* __restrict__ g, const void* __restrict__ bb, long goff, u16* __restrict__ out,
    const int* __restrict__ dflag){
  __shared__ float red[8];
  bool wf = dflag[0] != 0;
  int row = blockIdx.x, tid = threadIdx.x;
  const float* xr = x + (size_t)row * D_;
  float v[3]; float s = 0.f, s2 = 0.f;
  #pragma unroll
  for (int i = 0; i < 3; ++i){ float t = xr[tid + i*256]; v[i] = t; s += t; s2 += t*t; }
  #pragma unroll
  for (int o = 1; o < 64; o <<= 1){ s += __shfl_xor(s, o, 64); s2 += __shfl_xor(s2, o, 64); }
  if ((tid & 63) == 0){ red[tid >> 6] = s; red[(tid >> 6) + 4] = s2; }
  __syncthreads();
  s  = red[0] + red[1] + red[2] + red[3];
  s2 = red[4] + red[5] + red[6] + red[7];
  float mean = s * (1.f / D_);
  float var  = s2 * (1.f / D_) - mean * mean;
  float rstd = rsqrtf(var + 1e-5f);
  u16* orow = out + (size_t)row * D_;
  #pragma unroll
  for (int i = 0; i < 3; ++i){
    int d = tid + i*256;
    orow[d] = f2bf((v[i] - mean) * rstd * rdin(g, goff + d, wf) + rdin(bb, goff + d, wf));
  }
}

// ---------------- causal row softmax ----------------
__global__ __launch_bounds__(256) void softmax_k(const float* __restrict__ scores,
    float* __restrict__ attnf, u16* __restrict__ probsb, int writeAttn){
  __shared__ float red[4];
  int r = blockIdx.x, tid = threadIdx.x;
  int q = r & (T_-1);
  const float* srow = scores + (size_t)r * T_;
  u16* prow = probsb + (size_t)r * T_;
  int n = q + 1;
  float sv[4]; float mx = -1e30f;
  #pragma unroll
  for (int i = 0; i < 4; ++i){ int k = tid + i*256;
    float t = (k < n) ? srow[k] : -1e30f; sv[i] = t; mx = fmaxf(mx, t); }
  #pragma unroll
  for (int o = 1; o < 64; o <<= 1) mx = fmaxf(mx, __shfl_xor(mx, o, 64));
  if ((tid & 63) == 0) red[tid >> 6] = mx;
  __syncthreads();
  mx = fmaxf(fmaxf(red[0], red[1]), fmaxf(red[2], red[3]));
  __syncthreads();
  float e[4]; float sum = 0.f;
  #pragma unroll
  for (int i = 0; i < 4; ++i){ int k = tid + i*256;
    float t = (k < n) ? expf(sv[i] - mx) : 0.f; e[i] = t; sum += t; }
  #pragma unroll
  for (int o = 1; o < 64; o <<= 1) sum += __shfl_xor(sum, o, 64);
  if ((tid & 63) == 0) red[tid >> 6] = sum;
  __syncthreads();
  sum = red[0] + red[1] + red[2] + red[3];
  float inv = 1.f / sum;
  if (writeAttn){
    float* arow = attnf + (size_t)r * T_;
    #pragma unroll
    for (int i = 0; i < 4; ++i){ int k = tid + i*256;
      float p = (k < n) ? e[i] * inv : 0.f;
      arow[k] = p; prow[k] = f2bf(p); }
  } else {
    #pragma unroll
    for (int i = 0; i < 4; ++i){ int k = tid + i*256;
      prow[k] = (k < n) ? f2bf(e[i] * inv) : (u16)0; }
  }
}

// ---------------- transpose+convert: raw [R][C] (elem offset) -> bf16 [C][R] ----------------
__global__ __launch_bounds__(256) void transpose_k(const void* __restrict__ in, u16* __restrict__ outp,
                                                   int R, int C, long ielem, const int* __restrict__ dflag){
  __shared__ u16 tile[32][33];
  bool wf = dflag[0] != 0;
  int c0 = blockIdx.x * 32, r0 = blockIdx.y * 32;
  int lx = threadIdx.x & 31, ly = threadIdx.x >> 5;
  #pragma unroll
  for (int i = 0; i < 4; ++i){
    int r = r0 + ly + i*8, c = c0 + lx;
    tile[ly + i*8][lx] = (c < C) ? f2bf(rdin(in, ielem + (long)r * C + c, wf)) : (u16)0;
  }
  __syncthreads();
  #pragma unroll
  for (int i = 0; i < 4; ++i){
    int c = c0 + ly + i*8, r = r0 + lx;
    if (c < C) outp[(size_t)c * R + r] = tile[lx][ly + i*8];
  }
}

// ---------------- generic bf16 MFMA GEMM ----------------
// EPI: 0 bf16 store, 1 gelu->bf16, 2 f32 residual +=, 3 f32 store (LDS-staged coalesced, NO bias).
template<int EPI, bool BTRANS, bool CAUSAL>
__global__ __launch_bounds__(256) void gemm_k(
    const u16* __restrict__ A, const void* __restrict__ W, const void* __restrict__ bias,
    long welem, long belem,
    u16* __restrict__ Cbf, float* __restrict__ Cf32, const int* __restrict__ dflag, int swapxy,
    int N, int K, int lda, int ldw, int ldc,
    long sAb, long sAh, long sWb, long sWh, long sCb, long sCh, float scale)
{
  int bx = swapxy ? blockIdx.y : blockIdx.x;
  int by = swapxy ? blockIdx.x : blockIdx.y;
  int m0 = by * 64;
  int n0 = bx * 64;
  if (CAUSAL && n0 > m0) return;
  const bool wf = dflag && (dflag[0] != 0);
  int z = blockIdx.z;
  int b = z / H_, hh = z % H_;
  const u16* Ab = A + (size_t)((long)b * sAb + (long)hh * sAh);
  long Woff = welem + (long)b * sWb + (long)hh * sWh;
  size_t Coff = (size_t)((long)b * sCb + (long)hh * sCh);

  __shared__ __align__(16) u16 SMEM[2 * 64 * 72];
  u16 (*As)[72] = (u16(*)[72])SMEM;
  u16 (*Ws)[72] = (u16(*)[72])(SMEM + 64 * 72);

  int tid = threadIdx.x;
  int lane = tid & 63, wid = tid >> 6;
  int wr = wid >> 1, wc = wid & 1;
  int sr = tid >> 3;            // 0..31
  int sc = (tid & 7) << 3;      // 0..56

  f32x4 acc[2][2];
  #pragma unroll
  for (int i = 0; i < 2; ++i)
    #pragma unroll
    for (int j = 0; j < 2; ++j) acc[i][j] = (f32x4){0.f, 0.f, 0.f, 0.f};

  for (int k0 = 0; k0 < K; k0 += 64){
    {
      const u16* ga = Ab + (size_t)(m0 + sr) * lda + k0 + sc;
      *(int4*)(&As[sr][sc])      = *(const int4*)ga;
      *(int4*)(&As[sr + 32][sc]) = *(const int4*)(ga + (size_t)32 * lda);
    }
    if (BTRANS){
      const u16* Wb = (const u16*)W + Woff;
      int4 zv; zv.x = zv.y = zv.z = zv.w = 0;
      int n = n0 + sr;
      const u16* gw = Wb + (size_t)n * ldw + k0 + sc;
      *(int4*)(&Ws[sr][sc])      = (n      < N) ? *(const int4*)gw                      : zv;
      *(int4*)(&Ws[sr + 32][sc]) = (n + 32 < N) ? *(const int4*)(gw + (size_t)32 * ldw) : zv;
    } else if (wf){
      const float* Wb = (const float*)W + Woff;
      const float* gw = Wb + (size_t)(k0 + sr) * ldw + n0 + sc;
      if ((ldw & 3) == 0){
        float4 t0 = *(const float4*)gw;
        float4 t1 = *(const float4*)(gw + 4);
        Ws[sc+0][sr] = f2bf(t0.x); Ws[sc+1][sr] = f2bf(t0.y);
        Ws[sc+2][sr] = f2bf(t0.z); Ws[sc+3][sr] = f2bf(t0.w);
        Ws[sc+4][sr] = f2bf(t1.x); Ws[sc+5][sr] = f2bf(t1.y);
        Ws[sc+6][sr] = f2bf(t1.z); Ws[sc+7][sr] = f2bf(t1.w);
        t0 = *(const float4*)(gw + (size_t)32 * ldw);
        t1 = *(const float4*)(gw + (size_t)32 * ldw + 4);
        Ws[sc+0][sr+32] = f2bf(t0.x); Ws[sc+1][sr+32] = f2bf(t0.y);
        Ws[sc+2][sr+32] = f2bf(t0.z); Ws[sc+3][sr+32] = f2bf(t0.w);
        Ws[sc+4][sr+32] = f2bf(t1.x); Ws[sc+5][sr+32] = f2bf(t1.y);
        Ws[sc+6][sr+32] = f2bf(t1.z); Ws[sc+7][sr+32] = f2bf(t1.w);
      } else {
        #pragma unroll
        for (int j = 0; j < 8; ++j){
          bool ok = (n0 + sc + j) < N;
          Ws[sc + j][sr]      = ok ? f2bf(gw[j])                    : (u16)0;
          Ws[sc + j][sr + 32] = ok ? f2bf(gw[j + (size_t)32 * ldw]) : (u16)0;
        }
      }
    } else {
      const u16* Wb = (const u16*)W + Woff;
      const u16* gw = Wb + (size_t)(k0 + sr) * ldw + n0 + sc;
      u16 tmp[8];
      *(int4*)tmp = *(const int4*)gw;
      #pragma unroll
      for (int j = 0; j < 8; ++j) Ws[sc + j][sr] = tmp[j];
      *(int4*)tmp = *(const int4*)(gw + (size_t)32 * ldw);
      #pragma unroll
      for (int j = 0; j < 8; ++j) Ws[sc + j][sr + 32] = tmp[j];
    }
    __syncthreads();
    #pragma unroll
    for (int kk = 0; kk < 2; ++kk){
      int ko = kk * 32 + ((lane >> 4) << 3);
      bf16x8 af[2], bfr[2];
      #pragma unroll
      for (int mi = 0; mi < 2; ++mi)
        af[mi] = *(const bf16x8*)(&As[wr*32 + mi*16 + (lane & 15)][ko]);
      #pragma unroll
      for (int ni = 0; ni < 2; ++ni)
        bfr[ni] = *(const bf16x8*)(&Ws[wc*32 + ni*16 + (lane & 15)][ko]);
      #pragma unroll
      for (int mi = 0; mi < 2; ++mi)
        #pragma unroll
        for (int ni = 0; ni < 2; ++ni)
          acc[mi][ni] = __builtin_amdgcn_mfma_f32_16x16x32_bf16(af[mi], bfr[ni], acc[mi][ni], 0, 0, 0);
    }
    __syncthreads();
  }

  if (EPI == 3){
    // stage f32 tile in LDS (pad 68 -> 2-way max), then 256-B contiguous row writes
    float* flds = (float*)SMEM;                       // 64*68*4 = 17408 <= 18432
    #pragma unroll
    for (int ni = 0; ni < 2; ++ni){
      int colL = wc*32 + ni*16 + (lane & 15);
      #pragma unroll
      for (int mi = 0; mi < 2; ++mi){
        int rb = wr*32 + mi*16 + ((lane >> 4) << 2);
        #pragma unroll
        for (int r = 0; r < 4; ++r)
          flds[(rb + r)*68 + colL] = acc[mi][ni][r] * scale;
      }
    }
    __syncthreads();
    int nv = N - n0; if (nv > 64) nv = 64;
    #pragma unroll
    for (int p = 0; p < 4; ++p){
      int row = p*16 + (tid >> 4);
      int c0 = tid & 15;
      size_t rbase = Coff + (size_t)(m0 + row) * ldc + n0;
      #pragma unroll
      for (int j = 0; j < 4; ++j){
        int col = c0 + j*16;
        if (col < nv) Cf32[rbase + col] = flds[row*68 + col];
      }
    }
  } else {
    #pragma unroll
    for (int ni = 0; ni < 2; ++ni){
      int col = n0 + wc*32 + ni*16 + (lane & 15);
      if (col >= N) continue;
      float bvv = 0.f;
      if (bias) bvv = wf ? ((const float*)bias)[belem + col] : bf2f(((const u16*)bias)[belem + col]);
      #pragma unroll
      for (int mi = 0; mi < 2; ++mi){
        int rbase = m0 + wr*32 + mi*16 + ((lane >> 4) << 2);
        #pragma unroll
        for (int r = 0; r < 4; ++r){
          int row = rbase + r;
          float v = acc[mi][ni][r] * scale + bvv;
          size_t idx = Coff + (size_t)row * ldc + col;
          if (EPI == 0)      Cbf[idx] = f2bf(v);
          else if (EPI == 1){ float gg = 0.5f * v * (1.f + erff(v * 0.70710678118654752f)); Cbf[idx] = f2bf(gg); }
          else               Cf32[idx] += v;
        }
      }
    }
  }
}

extern "C" void kernel_launch(void* const* d_in, const int* in_sizes, int n_in,
                              void* d_out, int out_size, void* d_ws, size_t ws_size,
                              hipStream_t stream)
{
  (void)in_sizes; (void)n_in; (void)out_size;
  const int* ids = (const int*)d_in[0];
  const void* tok = d_in[1];  const void* pos = d_in[2];
  const void* ln1g = d_in[3]; const void* ln1b = d_in[4];
  const void* wq = d_in[5];   const void* bq = d_in[6];
  const void* wk = d_in[7];   const void* bk = d_in[8];
  const void* wv = d_in[9];   const void* bv = d_in[10];
  const void* wo = d_in[11];  const void* bo = d_in[12];
  const void* ln2g = d_in[13]; const void* ln2b = d_in[14];
  const void* w1 = d_in[15];  const void* b1 = d_in[16];
  const void* w2 = d_in[17];  const void* b2 = d_in[18];
  const void* lnfg = d_in[19]; const void* lnfb = d_in[20];
  const void* pw = d_in[21];

  // ---------- d_out (f32, 512.4 MB) memory map ----------
  //   logits f32 [0, 411,705,344)   attn f32 [411,705,344, 512,368,640)
  // scratch inside logits region (dead before projection):
  //   scores [0,100.7M) | x [100.7,107.0M) | qb,kb,vb,ctx,ff bf16 [107.0,132.1M)
  //   probsb bf16 [132.1, 182.5M) | wT bf16 (transposed weights) [182.5, 239.1M)
  char* ob = (char*)d_out;
  float* logitsF = (float*)ob;
  float* attnF   = (float*)(ob + 411705344);
  float* scores  = (float*)ob;
  float* x   = (float*)(ob + 100663296);
  u16* qb    = (u16*)(ob + 106954752);
  u16* kb    = (u16*)(ob + 110100480);
  u16* vb    = (u16*)(ob + 113246208);
  u16* ctx   = (u16*)(ob + 116391936);
  u16* ff    = (u16*)(ob + 119537664);
  u16* probsb= (u16*)(ob + 132120576);
  u16* wT    = (u16*)(ob + 182452224);          // 4 layers x 7,077,888 elems
  const long LSTR = 7077888;
  char* wsp = (char*)d_ws;
  int* dflag = (int*)wsp;
  u16* h     = (u16*)(wsp + 256);
  u16* projT = (u16*)(wsp + 256 + 3145728);
  bool useT = (ws_size >= (size_t)256 + 3145728 + (size_t)V_ * D_ * 2);

  const int BT = B_ * T_;
  detect_k<<<1, 256, 0, stream>>>((const u16*)tok, dflag);
  if (useT){
    dim3 gt((V_ + 31) / 32, D_ / 32);
    transpose_k<<<gt, 256, 0, stream>>>(pw, projT, D_, V_, 0, dflag);
  }
  // transpose+convert all layer weights to bf16 [N][K]
  {
    dim3 gDD(24, 24), g1(96, 24), g2(24, 96);
    for (int l = 0; l < L_; ++l){
      u16* base = wT + (size_t)l * LSTR;
      transpose_k<<<gDD, 256, 0, stream>>>(wq, base,                 D_, D_,  (long)l*D_*D_,  dflag);
      transpose_k<<<gDD, 256, 0, stream>>>(wk, base + 589824,        D_, D_,  (long)l*D_*D_,  dflag);
      transpose_k<<<gDD, 256, 0, stream>>>(wv, base + 2*589824,      D_, D_,  (long)l*D_*D_,  dflag);
      transpose_k<<<gDD, 256, 0, stream>>>(wo, base + 3*589824,      D_, D_,  (long)l*D_*D_,  dflag);
      transpose_k<<<g1, 256, 0, stream>>>(w1, base + 4*589824,       D_, FF_, (long)l*D_*FF_, dflag);
      transpose_k<<<g2, 256, 0, stream>>>(w2, base + 4*589824+2359296, FF_, D_, (long)l*FF_*D_, dflag);
    }
  }
  embed_k<<<BT, 256, 0, stream>>>(ids, tok, pos, x, dflag);

  dim3 gD(D_/64, BT/64);            // 12 x 32
  dim3 gFF(FF_/64, BT/64);          // 48 x 32
  dim3 gS(T_/64, T_/64, B_*H_);
  dim3 gC(1, T_/64, B_*H_);

  const long sQKb = (long)T_ * D_, sQKh = DK_;
  const long sSb  = (long)H_ * T_ * T_, sSh = (long)T_ * T_;

  for (int l = 0; l < L_; ++l){
    long oB = (long)l * D_, oB1 = (long)l * FF_;
    u16* wqT = wT + (size_t)l * LSTR;
    u16* wkT = wqT + 589824;
    u16* wvT = wqT + 2*589824;
    u16* woT = wqT + 3*589824;
    u16* w1T = wqT + 4*589824;
    u16* w2T = w1T + 2359296;
    ln_k<<<BT, 256, 0, stream>>>(x, ln1g, ln1b, oB, h, dflag);
    gemm_k<0,true,false><<<gD, 256, 0, stream>>>(h, wqT, bq, 0, oB, qb, nullptr, dflag, 0,
        D_, D_, D_, D_, D_, 0,0,0,0,0,0, 1.f);
    gemm_k<0,true,false><<<gD, 256, 0, stream>>>(h, wkT, bk, 0, oB, kb, nullptr, dflag, 0,
        D_, D_, D_, D_, D_, 0,0,0,0,0,0, 1.f);
    gemm_k<0,true,false><<<gD, 256, 0, stream>>>(h, wvT, bv, 0, oB, vb, nullptr, dflag, 0,
        D_, D_, D_, D_, D_, 0,0,0,0,0,0, 1.f);
    gemm_k<3,true,true><<<gS, 256, 0, stream>>>(qb, kb, nullptr, 0, 0, nullptr, scores, nullptr, 0,
        T_, DK_, D_, D_, T_, sQKb, sQKh, sQKb, sQKh, sSb, sSh, 0.125f);
    softmax_k<<<B_*H_*T_, 256, 0, stream>>>(scores, attnF, probsb, (l == L_-1) ? 1 : 0);
    gemm_k<0,false,false><<<gC, 256, 0, stream>>>(probsb, vb, nullptr, 0, 0, ctx, nullptr, nullptr, 0,
        DK_, T_, T_, D_, D_, sSb, sSh, sQKb, sQKh, sQKb, sQKh, 1.f);
    gemm_k<2,true,false><<<gD, 256, 0, stream>>>(ctx, woT, bo, 0, oB, nullptr, x, dflag, 0,
        D_, D_, D_, D_, D_, 0,0,0,0,0,0, 1.f);
    ln_k<<<BT, 256, 0, stream>>>(x, ln2g, ln2b, oB, h, dflag);
    gemm_k<1,true,false><<<gFF, 256, 0, stream>>>(h, w1T, b1, 0, oB1, ff, nullptr, dflag, 0,
        FF_, D_, D_, D_, FF_, 0,0,0,0,0,0, 1.f);
    gemm_k<2,true,false><<<gD, 256, 0, stream>>>(ff, w2T, b2, 0, oB, nullptr, x, dflag, 0,
        D_, FF_, FF_, FF_, D_, 0,0,0,0,0,0, 1.f);
  }
  ln_k<<<BT, 256, 0, stream>>>(x, lnfg, lnfb, 0, h, dflag);
  // projection: m-fastest grid (swapxy=1) for W reuse in L2
  if (useT){
    dim3 gP(BT / 64, (V_ + 63) / 64);
    gemm_k<3,true,false><<<gP, 256, 0, stream>>>(h, projT, nullptr, 0, 0, nullptr, logitsF, nullptr, 1,
        V_, D_, D_, D_, V_, 0,0,0,0,0,0, 1.f);
  } else {
    dim3 gP(BT / 64, (V_ + 63) / 64);
    gemm_k<3,false,false><<<gP, 256, 0, stream>>>(h, pw, nullptr, 0, 0, nullptr, logitsF, dflag, 1,
        V_, D_, D_, V_, V_, 0,0,0,0,0,0, 1.f);
  }
}

// Round 10
// 1622.888 us; speedup vs baseline: 1.2495x; 1.2340x over previous
//
#include <hip/hip_runtime.h>

typedef unsigned short u16;
typedef __bf16 bf16x8 __attribute__((ext_vector_type(8)));
typedef float f32x4 __attribute__((ext_vector_type(4)));

#define L_ 4
#define D_ 768
#define T_ 1024
#define B_ 2
#define H_ 12
#define DK_ 64
#define FF_ 3072
#define V_ 50257

__device__ __forceinline__ float bf2f(u16 u){ return __uint_as_float(((unsigned)u) << 16); }
__device__ __forceinline__ u16 f2bf(float f){
  unsigned x = __float_as_uint(f);
  return (u16)((x + 0x7fffu + ((x >> 16) & 1u)) >> 16);   // RNE
}

// ---- input dtype probe (HW-proven f32; kept as insurance) ----
__global__ __launch_bounds__(256) void detect_k(const u16* __restrict__ w, int* __restrict__ flag){
  __shared__ int s;
  if (threadIdx.x == 0) s = 0;
  __syncthreads();
  int bad = 0;
  for (int j = threadIdx.x; j < 4096; j += 256){
    int e = (w[j] >> 7) & 0xFF;
    if (e >= 0xC0) bad = 1;
  }
  if (bad) atomicOr(&s, 1);
  __syncthreads();
  if (threadIdx.x == 0) flag[0] = s;
}

__device__ __forceinline__ float rdin(const void* p, long i, bool wf){
  return wf ? ((const float*)p)[i] : bf2f(((const u16*)p)[i]);
}

// ---------------- embedding ----------------
__global__ __launch_bounds__(256) void embed_k(const int* __restrict__ ids,
    const void* __restrict__ tok, const void* __restrict__ pos, float* __restrict__ x,
    const int* __restrict__ dflag){
  bool wf = dflag[0] != 0;
  int row = blockIdx.x; int t = row & (T_-1);
  long id = ids[row];
  float* xr = x + (size_t)row * D_;
  for (int d = threadIdx.x; d < D_; d += 256)
    xr[d] = rdin(tok, id * (long)D_ + d, wf) + rdin(pos, (long)t * D_ + d, wf);
}

// ---------------- layernorm: f32 x -> bf16 h ----------------
__global__ __launch_bounds__(256) void ln_k(const float* __restrict__ x,
    const void* __restrict__ g, const void* __restrict__ bb, long goff, u16* __restrict__ out,
    const int* __restrict__ dflag){
  __shared__ float red[8];
  bool wf = dflag[0] != 0;
  int row = blockIdx.x, tid = threadIdx.x;
  const float* xr = x + (size_t)row * D_;
  float v[3]; float s = 0.f, s2 = 0.f;
  #pragma unroll
  for (int i = 0; i < 3; ++i){ float t = xr[tid + i*256]; v[i] = t; s += t; s2 += t*t; }
  #pragma unroll
  for (int o = 1; o < 64; o <<= 1){ s += __shfl_xor(s, o, 64); s2 += __shfl_xor(s2, o, 64); }
  if ((tid & 63) == 0){ red[tid >> 6] = s; red[(tid >> 6) + 4] = s2; }
  __syncthreads();
  s  = red[0] + red[1] + red[2] + red[3];
  s2 = red[4] + red[5] + red[6] + red[7];
  float mean = s * (1.f / D_);
  float var  = s2 * (1.f / D_) - mean * mean;
  float rstd = rsqrtf(var + 1e-5f);
  u16* orow = out + (size_t)row * D_;
  #pragma unroll
  for (int i = 0; i < 3; ++i){
    int d = tid + i*256;
    orow[d] = f2bf((v[i] - mean) * rstd * rdin(g, goff + d, wf) + rdin(bb, goff + d, wf));
  }
}

// ---------------- causal row softmax ----------------
__global__ __launch_bounds__(256) void softmax_k(const float* __restrict__ scores,
    float* __restrict__ attnf, u16* __restrict__ probsb, int writeAttn){
  __shared__ float red[4];
  int r = blockIdx.x, tid = threadIdx.x;
  int q = r & (T_-1);
  const float* srow = scores + (size_t)r * T_;
  u16* prow = probsb + (size_t)r * T_;
  int n = q + 1;
  float sv[4]; float mx = -1e30f;
  #pragma unroll
  for (int i = 0; i < 4; ++i){ int k = tid + i*256;
    float t = (k < n) ? srow[k] : -1e30f; sv[i] = t; mx = fmaxf(mx, t); }
  #pragma unroll
  for (int o = 1; o < 64; o <<= 1) mx = fmaxf(mx, __shfl_xor(mx, o, 64));
  if ((tid & 63) == 0) red[tid >> 6] = mx;
  __syncthreads();
  mx = fmaxf(fmaxf(red[0], red[1]), fmaxf(red[2], red[3]));
  __syncthreads();
  float e[4]; float sum = 0.f;
  #pragma unroll
  for (int i = 0; i < 4; ++i){ int k = tid + i*256;
    float t = (k < n) ? expf(sv[i] - mx) : 0.f; e[i] = t; sum += t; }
  #pragma unroll
  for (int o = 1; o < 64; o <<= 1) sum += __shfl_xor(sum, o, 64);
  if ((tid & 63) == 0) red[tid >> 6] = sum;
  __syncthreads();
  sum = red[0] + red[1] + red[2] + red[3];
  float inv = 1.f / sum;
  if (writeAttn){
    float* arow = attnf + (size_t)r * T_;
    #pragma unroll
    for (int i = 0; i < 4; ++i){ int k = tid + i*256;
      float p = (k < n) ? e[i] * inv : 0.f;
      arow[k] = p; prow[k] = f2bf(p); }
  } else {
    #pragma unroll
    for (int i = 0; i < 4; ++i){ int k = tid + i*256;
      prow[k] = (k < n) ? f2bf(e[i] * inv) : (u16)0; }
  }
}

// ---------------- transpose+convert: raw [R][ldin] window -> bf16 [C][R] ----------------
__global__ __launch_bounds__(256) void transpose_k(const void* __restrict__ in, u16* __restrict__ outp,
                                                   int R, int C, int ldin, long ielem,
                                                   const int* __restrict__ dflag){
  __shared__ u16 tile[32][33];
  bool wf = dflag[0] != 0;
  int c0 = blockIdx.x * 32, r0 = blockIdx.y * 32;
  int lx = threadIdx.x & 31, ly = threadIdx.x >> 5;
  #pragma unroll
  for (int i = 0; i < 4; ++i){
    int r = r0 + ly + i*8, c = c0 + lx;
    tile[ly + i*8][lx] = (c < C) ? f2bf(rdin(in, ielem + (long)r * ldin + c, wf)) : (u16)0;
  }
  __syncthreads();
  #pragma unroll
  for (int i = 0; i < 4; ++i){
    int c = c0 + ly + i*8, r = r0 + lx;
    if (c < C) outp[(size_t)c * R + r] = tile[lx][ly + i*8];
  }
}

// ---------------- qkv bias concat -> bf16 [L][2304] ----------------
__global__ __launch_bounds__(256) void bcat_k(const void* __restrict__ bq, const void* __restrict__ bk,
    const void* __restrict__ bv, u16* __restrict__ outp, const int* __restrict__ dflag){
  bool wf = dflag[0] != 0;
  int l = blockIdx.x;
  for (int j = threadIdx.x; j < 3*D_; j += 256){
    float v;
    if (j < D_)        v = rdin(bq, (long)l*D_ + j, wf);
    else if (j < 2*D_) v = rdin(bk, (long)l*D_ + j - D_, wf);
    else               v = rdin(bv, (long)l*D_ + j - 2*D_, wf);
    outp[(size_t)l*3*D_ + j] = f2bf(v);
  }
}

// ---------------- generic 64-tile bf16 MFMA GEMM (HW-verified maps) ----------------
// EPI: 0 bf16 store, 1 gelu->bf16, 2 f32 residual +=, 3 f32 store (LDS-staged).
template<int EPI, bool BTRANS, bool CAUSAL>
__global__ __launch_bounds__(256) void gemm_k(
    const u16* __restrict__ A, const void* __restrict__ W, const void* __restrict__ bias,
    long welem, long belem,
    u16* __restrict__ Cbf, float* __restrict__ Cf32, const int* __restrict__ dflag,
    int N, int K, int lda, int ldw, int ldc,
    long sAb, long sAh, long sWb, long sWh, long sCb, long sCh, float scale)
{
  int m0 = blockIdx.y * 64;
  int n0 = blockIdx.x * 64;
  if (CAUSAL && n0 > m0) return;
  const bool wf = dflag && (dflag[0] != 0);
  int z = blockIdx.z;
  int b = z / H_, hh = z % H_;
  const u16* Ab = A + (size_t)((long)b * sAb + (long)hh * sAh);
  long Woff = welem + (long)b * sWb + (long)hh * sWh;
  size_t Coff = (size_t)((long)b * sCb + (long)hh * sCh);

  __shared__ __align__(16) u16 SMEM[2 * 64 * 72];
  u16 (*As)[72] = (u16(*)[72])SMEM;
  u16 (*Ws)[72] = (u16(*)[72])(SMEM + 64 * 72);

  int tid = threadIdx.x;
  int lane = tid & 63, wid = tid >> 6;
  int wr = wid >> 1, wc = wid & 1;
  int sr = tid >> 3;
  int sc = (tid & 7) << 3;

  f32x4 acc[2][2];
  #pragma unroll
  for (int i = 0; i < 2; ++i)
    #pragma unroll
    for (int j = 0; j < 2; ++j) acc[i][j] = (f32x4){0.f, 0.f, 0.f, 0.f};

  for (int k0 = 0; k0 < K; k0 += 64){
    {
      const u16* ga = Ab + (size_t)(m0 + sr) * lda + k0 + sc;
      *(int4*)(&As[sr][sc])      = *(const int4*)ga;
      *(int4*)(&As[sr + 32][sc]) = *(const int4*)(ga + (size_t)32 * lda);
    }
    if (BTRANS){
      const u16* Wb = (const u16*)W + Woff;
      int4 zv; zv.x = zv.y = zv.z = zv.w = 0;
      int n = n0 + sr;
      const u16* gw = Wb + (size_t)n * ldw + k0 + sc;
      *(int4*)(&Ws[sr][sc])      = (n      < N) ? *(const int4*)gw                      : zv;
      *(int4*)(&Ws[sr + 32][sc]) = (n + 32 < N) ? *(const int4*)(gw + (size_t)32 * ldw) : zv;
    } else if (wf){
      const float* Wb = (const float*)W + Woff;
      const float* gw = Wb + (size_t)(k0 + sr) * ldw + n0 + sc;
      #pragma unroll
      for (int j = 0; j < 8; ++j){
        bool ok = (n0 + sc + j) < N;
        Ws[sc + j][sr]      = ok ? f2bf(gw[j])                    : (u16)0;
        Ws[sc + j][sr + 32] = ok ? f2bf(gw[j + (size_t)32 * ldw]) : (u16)0;
      }
    } else {
      const u16* Wb = (const u16*)W + Woff;
      const u16* gw = Wb + (size_t)(k0 + sr) * ldw + n0 + sc;
      u16 tmp[8];
      *(int4*)tmp = *(const int4*)gw;
      #pragma unroll
      for (int j = 0; j < 8; ++j) Ws[sc + j][sr] = tmp[j];
      *(int4*)tmp = *(const int4*)(gw + (size_t)32 * ldw);
      #pragma unroll
      for (int j = 0; j < 8; ++j) Ws[sc + j][sr + 32] = tmp[j];
    }
    __syncthreads();
    #pragma unroll
    for (int kk = 0; kk < 2; ++kk){
      int ko = kk * 32 + ((lane >> 4) << 3);
      bf16x8 af[2], bfr[2];
      #pragma unroll
      for (int mi = 0; mi < 2; ++mi)
        af[mi] = *(const bf16x8*)(&As[wr*32 + mi*16 + (lane & 15)][ko]);
      #pragma unroll
      for (int ni = 0; ni < 2; ++ni)
        bfr[ni] = *(const bf16x8*)(&Ws[wc*32 + ni*16 + (lane & 15)][ko]);
      #pragma unroll
      for (int mi = 0; mi < 2; ++mi)
        #pragma unroll
        for (int ni = 0; ni < 2; ++ni)
          acc[mi][ni] = __builtin_amdgcn_mfma_f32_16x16x32_bf16(af[mi], bfr[ni], acc[mi][ni], 0, 0, 0);
    }
    __syncthreads();
  }

  if (EPI == 3){
    float* flds = (float*)SMEM;
    #pragma unroll
    for (int ni = 0; ni < 2; ++ni){
      int colL = wc*32 + ni*16 + (lane & 15);
      #pragma unroll
      for (int mi = 0; mi < 2; ++mi){
        int rb = wr*32 + mi*16 + ((lane >> 4) << 2);
        #pragma unroll
        for (int r = 0; r < 4; ++r)
          flds[(rb + r)*68 + colL] = acc[mi][ni][r] * scale;
      }
    }
    __syncthreads();
    int nv = N - n0; if (nv > 64) nv = 64;
    #pragma unroll
    for (int p = 0; p < 4; ++p){
      int row = p*16 + (tid >> 4);
      int c0 = tid & 15;
      size_t rbase = Coff + (size_t)(m0 + row) * ldc + n0;
      #pragma unroll
      for (int j = 0; j < 4; ++j){
        int col = c0 + j*16;
        if (col < nv) Cf32[rbase + col] = flds[row*68 + col];
      }
    }
  } else {
    #pragma unroll
    for (int ni = 0; ni < 2; ++ni){
      int col = n0 + wc*32 + ni*16 + (lane & 15);
      if (col >= N) continue;
      float bvv = 0.f;
      if (bias) bvv = wf ? ((const float*)bias)[belem + col] : bf2f(((const u16*)bias)[belem + col]);
      #pragma unroll
      for (int mi = 0; mi < 2; ++mi){
        int rbase = m0 + wr*32 + mi*16 + ((lane >> 4) << 2);
        #pragma unroll
        for (int r = 0; r < 4; ++r){
          int row = rbase + r;
          float v = acc[mi][ni][r] * scale + bvv;
          size_t idx = Coff + (size_t)row * ldc + col;
          if (EPI == 0)      Cbf[idx] = f2bf(v);
          else if (EPI == 1){ float gg = 0.5f * v * (1.f + erff(v * 0.70710678118654752f)); Cbf[idx] = f2bf(gg); }
          else               Cf32[idx] += v;
        }
      }
    }
  }
}

// ---------------- 128x128 m97-structure GEMM: C(f32) = A(bf16[M][K]) @ Wt(bf16[N][K])^T ----
// global_load_lds w=16, linear LDS + XOR-swizzled source/read (T2, rule 21), 4 waves x 64x64.
__global__ __launch_bounds__(256) void gemm128_k(
    const u16* __restrict__ A, const u16* __restrict__ Wt, float* __restrict__ C,
    int N, int K, int lda, int ldw, int ldc)
{
  int m0 = blockIdx.x * 128;          // m-fastest for W L2 reuse
  int n0 = blockIdx.y * 128;
  __shared__ __align__(16) u16 SM[2 * 128 * 64];
  u16* As = SM;
  u16* Ws = SM + 128 * 64;

  int tid = threadIdx.x, lane = tid & 63, wid = tid >> 6;
  int wr = wid >> 1, wc = wid & 1;
  int l8 = lane >> 3;                 // row within 8-row chunk
  int sl = (lane & 7) ^ l8;           // inverse-swizzled source 16B-slot

  f32x4 acc[4][4];
  #pragma unroll
  for (int i = 0; i < 4; ++i)
    #pragma unroll
    for (int j = 0; j < 4; ++j) acc[i][j] = (f32x4){0.f, 0.f, 0.f, 0.f};

  for (int k0 = 0; k0 < K; k0 += 64){
    #pragma unroll
    for (int j = 0; j < 4; ++j){
      int c = wid * 4 + j;
      const u16* ga = A  + (size_t)(m0 + 8*c + l8) * lda + k0 + sl*8;
      const u16* gw = Wt + (size_t)(n0 + 8*c + l8) * ldw + k0 + sl*8;
      __builtin_amdgcn_global_load_lds((const __attribute__((address_space(1))) void*)ga,
          (__attribute__((address_space(3))) void*)(As + c*512), 16, 0, 0);
      __builtin_amdgcn_global_load_lds((const __attribute__((address_space(1))) void*)gw,
          (__attribute__((address_space(3))) void*)(Ws + c*512), 16, 0, 0);
    }
    __syncthreads();
    #pragma unroll
    for (int kk = 0; kk < 2; ++kk){
      int slot = kk*4 + (lane >> 4);
      bf16x8 av[4], bv[4];
      #pragma unroll
      for (int mi = 0; mi < 4; ++mi){
        int r = wr*64 + mi*16 + (lane & 15);
        av[mi] = *(const bf16x8*)(As + r*64 + ((slot ^ (r & 7)) << 3));
      }
      #pragma unroll
      for (int ni = 0; ni < 4; ++ni){
        int r = wc*64 + ni*16 + (lane & 15);
        bv[ni] = *(const bf16x8*)(Ws + r*64 + ((slot ^ (r & 7)) << 3));
      }
      #pragma unroll
      for (int mi = 0; mi < 4; ++mi)
        #pragma unroll
        for (int ni = 0; ni < 4; ++ni)
          acc[mi][ni] = __builtin_amdgcn_mfma_f32_16x16x32_bf16(av[mi], bv[ni], acc[mi][ni], 0, 0, 0);
    }
    __syncthreads();
  }

  // epilogue: stage 64x128 f32 halves in LDS, coalesced 256-B row stores
  float* flds = (float*)SM;           // 64*128*4 = 32768 B
  #pragma unroll
  for (int hf = 0; hf < 2; ++hf){
    if (wr == hf){
      #pragma unroll
      for (int mi = 0; mi < 4; ++mi){
        int rb = mi*16 + ((lane >> 4) << 2);
        #pragma unroll
        for (int ni = 0; ni < 4; ++ni){
          int colL = wc*64 + ni*16 + (lane & 15);
          #pragma unroll
          for (int r = 0; r < 4; ++r)
            flds[(rb + r)*128 + colL] = acc[mi][ni][r];
        }
      }
    }
    __syncthreads();
    int c = tid & 127;
    int gc = n0 + c;
    if (gc < N){
      for (int rr = (tid >> 7); rr < 64; rr += 2)
        C[(size_t)(m0 + hf*64 + rr) * ldc + gc] = flds[rr*128 + c];
    }
    __syncthreads();
  }
}

extern "C" void kernel_launch(void* const* d_in, const int* in_sizes, int n_in,
                              void* d_out, int out_size, void* d_ws, size_t ws_size,
                              hipStream_t stream)
{
  (void)in_sizes; (void)n_in; (void)out_size; (void)ws_size;
  const int* ids = (const int*)d_in[0];
  const void* tok = d_in[1];  const void* pos = d_in[2];
  const void* ln1g = d_in[3]; const void* ln1b = d_in[4];
  const void* wq = d_in[5];   const void* bq = d_in[6];
  const void* wk = d_in[7];   const void* bk = d_in[8];
  const void* wv = d_in[9];   const void* bv = d_in[10];
  const void* wo = d_in[11];  const void* bo = d_in[12];
  const void* ln2g = d_in[13]; const void* ln2b = d_in[14];
  const void* w1 = d_in[15];  const void* b1 = d_in[16];
  const void* w2 = d_in[17];  const void* b2 = d_in[18];
  const void* lnfg = d_in[19]; const void* lnfb = d_in[20];
  const void* pw = d_in[21];

  // ---------- d_out (f32, 512.4 MB): logits [0, 411,705,344) | attn [411,705,344, end) ----------
  // scratch (dead before projection): scores [0,100.7M) | x | qkv | ctx | ff | wT+biascat | probsb
  char* ob = (char*)d_out;
  float* logitsF = (float*)ob;
  float* attnF   = (float*)(ob + 411705344);
  float* scores  = (float*)ob;
  float* x    = (float*)(ob + 100663296);
  u16* qkv    = (u16*)(ob + 106954752);          // [2048][2304] bf16
  u16* ctx    = (u16*)(ob + 116391936);
  u16* ff     = (u16*)(ob + 119537664);
  u16* wT     = (u16*)(ob + 132120576);          // 4 layers x 7,077,888 elems
  u16* biascat= (u16*)(ob + 188743680);          // [4][2304] bf16
  u16* probsb = (u16*)(ob + 188762112);          // [B,H,T,T] bf16
  const long LSTR = 7077888;
  char* wsp = (char*)d_ws;
  int* dflag = (int*)wsp;
  u16* h      = (u16*)(wsp + 256);               // [2048][768] bf16 (live during projection)
  u16* chunkT = (u16*)(wsp + 256 + 3145728);     // [12544][768] bf16 = 19.3 MB (ws >= 35 MB proven r2==r3)

  const int BT = B_ * T_;
  detect_k<<<1, 256, 0, stream>>>((const u16*)tok, dflag);
  bcat_k<<<L_, 256, 0, stream>>>(bq, bk, bv, biascat, dflag);
  {
    dim3 gDD(24, 24), g1(96, 24), g2(24, 96);
    for (int l = 0; l < L_; ++l){
      u16* base = wT + (size_t)l * LSTR;
      transpose_k<<<gDD, 256, 0, stream>>>(wq, base,                  D_, D_,  D_,  (long)l*D_*D_,  dflag);
      transpose_k<<<gDD, 256, 0, stream>>>(wk, base + 589824,         D_, D_,  D_,  (long)l*D_*D_,  dflag);
      transpose_k<<<gDD, 256, 0, stream>>>(wv, base + 2*589824,       D_, D_,  D_,  (long)l*D_*D_,  dflag);
      transpose_k<<<gDD, 256, 0, stream>>>(wo, base + 3*589824,       D_, D_,  D_,  (long)l*D_*D_,  dflag);
      transpose_k<<<g1, 256, 0, stream>>>(w1, base + 4*589824,        D_, FF_, FF_, (long)l*D_*FF_, dflag);
      transpose_k<<<g2, 256, 0, stream>>>(w2, base + 4*589824+2359296, FF_, D_, D_, (long)l*FF_*D_, dflag);
    }
  }
  embed_k<<<BT, 256, 0, stream>>>(ids, tok, pos, x, dflag);

  dim3 gQKV(36, 32);                 // N=2304
  dim3 gD(12, 32);
  dim3 gFF(48, 32);
  dim3 gS(16, 16, B_*H_);
  dim3 gC(1, 16, B_*H_);

  const long sQb = (long)T_ * 3*D_;  // qkv batch stride
  const long sSb = (long)H_ * T_ * T_, sSh = (long)T_ * T_;

  for (int l = 0; l < L_; ++l){
    long oB = (long)l * D_, oB1 = (long)l * FF_;
    u16* wl  = wT + (size_t)l * LSTR;          // [2304][768] = wq|wk|wv rows
    u16* woT = wl + 3*589824;
    u16* w1T = wl + 4*589824;
    u16* w2T = w1T + 2359296;
    ln_k<<<BT, 256, 0, stream>>>(x, ln1g, ln1b, oB, h, dflag);
    // fused qkv = h @ [wq|wk|wv]^T + bias   -> [2048][2304]
    gemm_k<0,true,false><<<gQKV, 256, 0, stream>>>(h, wl, biascat, 0, (long)l*3*D_, qkv, nullptr, nullptr,
        3*D_, D_, D_, D_, 3*D_, 0,0,0,0,0,0, 1.f);
    // scores = (Q @ K^T)/8
    gemm_k<3,true,true><<<gS, 256, 0, stream>>>(qkv, qkv, nullptr, D_, 0, nullptr, scores, nullptr,
        T_, DK_, 3*D_, 3*D_, T_, sQb, 64, sQb, 64, sSb, sSh, 0.125f);
    softmax_k<<<B_*H_*T_, 256, 0, stream>>>(scores, attnF, probsb, (l == L_-1) ? 1 : 0);
    // ctx = P @ V
    gemm_k<0,false,false><<<gC, 256, 0, stream>>>(probsb, qkv, nullptr, 2*D_, 0, ctx, nullptr, nullptr,
        DK_, T_, T_, 3*D_, D_, sSb, sSh, sQb, 64, (long)T_*D_, 64, 1.f);
    // x += ctx @ wo + bo
    gemm_k<2,true,false><<<gD, 256, 0, stream>>>(ctx, woT, bo, 0, oB, nullptr, x, dflag,
        D_, D_, D_, D_, D_, 0,0,0,0,0,0, 1.f);
    ln_k<<<BT, 256, 0, stream>>>(x, ln2g, ln2b, oB, h, dflag);
    gemm_k<1,true,false><<<gFF, 256, 0, stream>>>(h, w1T, b1, 0, oB1, ff, nullptr, dflag,
        FF_, D_, D_, D_, FF_, 0,0,0,0,0,0, 1.f);
    gemm_k<2,true,false><<<gD, 256, 0, stream>>>(ff, w2T, b2, 0, oB, nullptr, x, dflag,
        D_, FF_, FF_, FF_, D_, 0,0,0,0,0,0, 1.f);
  }
  ln_k<<<BT, 256, 0, stream>>>(x, lnfg, lnfb, 0, h, dflag);
  // projection in N-chunks: transpose pw chunk into ws, then 128^2 GEMM
  {
    const int CHUNK = 12544;   // 98 * 128
    int done = 0;
    while (done < V_){
      int cols = V_ - done; if (cols > CHUNK) cols = CHUNK;
      dim3 gt((cols + 31) / 32, 24);
      transpose_k<<<gt, 256, 0, stream>>>(pw, chunkT, D_, cols, V_, (long)done, dflag);
      dim3 gp(16, (cols + 127) / 128);
      gemm128_k<<<gp, 256, 0, stream>>>(h, chunkT, logitsF + done, cols, D_, D_, D_, V_);
      done += cols;
    }
  }
}